// Round 1
// baseline (11387.429 us; speedup 1.0000x reference)
//
#include <hip/hip_runtime.h>
#include <math.h>

#define DN   256      // node/hidden dim
#define BM   32       // rows per GEMM block
#define BK   32       // k-tile
#define PADY 36
#define PADW 36
#define LN_EPS 1e-5f

__global__ __launch_bounds__(256) void deg_count(const int* __restrict__ ei,
                                                 float* __restrict__ deg, int E) {
    int e = blockIdx.x * 256 + threadIdx.x;
    if (e < E) unsafeAtomicAdd(&deg[ei[e]], 1.0f);
}

// one 64-lane wave per edge: gather x[col] (float4/lane), atomic-add into agg[row]
__global__ __launch_bounds__(256) void scatter_add(const float* __restrict__ x,
                                                   const int* __restrict__ ei,
                                                   float* __restrict__ agg, int E) {
    int wid  = (blockIdx.x * 256 + threadIdx.x) >> 6;
    int lane = threadIdx.x & 63;
    if (wid >= E) return;
    int r = ei[wid];        // destination (row)
    int c = ei[E + wid];    // source (col)
    float4 v = reinterpret_cast<const float4*>(x + (size_t)c * DN)[lane];
    float* dst = agg + (size_t)r * DN + (size_t)lane * 4;
    unsafeAtomicAdd(dst + 0, v.x);
    unsafeAtomicAdd(dst + 1, v.y);
    unsafeAtomicAdd(dst + 2, v.z);
    unsafeAtomicAdd(dst + 3, v.w);
}

// fused: y = x + agg/max(deg,1);  h = y @ W^T + b;  LayerNorm;  SiLU
// block: 256 threads, 32 rows x 256 cols. thread(tx,ty): rows {2ty,2ty+1}, cols {tx+16c}
__global__ __launch_bounds__(256) void gemm_ln_silu(
        const float* __restrict__ x, const float* __restrict__ agg,
        const float* __restrict__ deg, const float* __restrict__ W,
        const float* __restrict__ bias, const float* __restrict__ gam,
        const float* __restrict__ bet, float* __restrict__ out, int N) {
    __shared__ float y_lds[BM][PADY];
    __shared__ float w_lds[DN][PADW];
    __shared__ float inv_lds[BM];

    int tid = threadIdx.x;
    int tx = tid & 15, ty = tid >> 4;
    int n0 = blockIdx.x * BM;

    if (tid < BM) {
        int n = n0 + tid;
        float d = (n < N) ? deg[n] : 1.0f;
        inv_lds[tid] = 1.0f / fmaxf(d, 1.0f);
    }

    float bv[16], gv[16], btv[16];
#pragma unroll
    for (int c2 = 0; c2 < 16; ++c2) {
        int j = tx + 16 * c2;
        bv[c2]  = bias[j];
        gv[c2]  = gam[j];
        btv[c2] = bet[j];
    }
    float acc0[16], acc1[16];
#pragma unroll
    for (int c2 = 0; c2 < 16; ++c2) { acc0[c2] = 0.f; acc1[c2] = 0.f; }

    __syncthreads();  // inv_lds ready

    int sr = tid >> 3;           // staging row 0..31
    int sq = (tid & 7) * 4;      // staging float4 offset within k-tile

    for (int kt = 0; kt < DN / BK; ++kt) {
        int k0 = kt * BK;
        __syncthreads();
        // stage W[j][k0..k0+31] -> w_lds[j][kk]
#pragma unroll
        for (int i = 0; i < 8; ++i) {
            int j = i * 32 + (tid >> 3);
            float4 wv = *reinterpret_cast<const float4*>(&W[(size_t)j * DN + k0 + sq]);
            *reinterpret_cast<float4*>(&w_lds[j][sq]) = wv;
        }
        // stage y slice
        {
            int n = n0 + sr;
            float4 yv = make_float4(0.f, 0.f, 0.f, 0.f);
            if (n < N) {
                float4 xv = *reinterpret_cast<const float4*>(&x[(size_t)n * DN + k0 + sq]);
                float4 av = *reinterpret_cast<const float4*>(&agg[(size_t)n * DN + k0 + sq]);
                float iv = inv_lds[sr];
                yv = make_float4(xv.x + av.x * iv, xv.y + av.y * iv,
                                 xv.z + av.z * iv, xv.w + av.w * iv);
            }
            *reinterpret_cast<float4*>(&y_lds[sr][sq]) = yv;
        }
        __syncthreads();
        // compute
#pragma unroll
        for (int q = 0; q < 8; ++q) {
            float4 y0 = *reinterpret_cast<const float4*>(&y_lds[2 * ty + 0][4 * q]);
            float4 y1 = *reinterpret_cast<const float4*>(&y_lds[2 * ty + 1][4 * q]);
#pragma unroll
            for (int c2 = 0; c2 < 16; ++c2) {
                float4 wv = *reinterpret_cast<const float4*>(&w_lds[tx + 16 * c2][4 * q]);
                acc0[c2] += y0.x * wv.x + y0.y * wv.y + y0.z * wv.z + y0.w * wv.w;
                acc1[c2] += y1.x * wv.x + y1.y * wv.y + y1.z * wv.z + y1.w * wv.w;
            }
        }
    }

    // bias
#pragma unroll
    for (int c2 = 0; c2 < 16; ++c2) { acc0[c2] += bv[c2]; acc1[c2] += bv[c2]; }

    // LayerNorm across the 16 tx-lanes holding this row
    float s0 = 0.f, s1 = 0.f;
#pragma unroll
    for (int c2 = 0; c2 < 16; ++c2) { s0 += acc0[c2]; s1 += acc1[c2]; }
#pragma unroll
    for (int m = 1; m < 16; m <<= 1) { s0 += __shfl_xor(s0, m); s1 += __shfl_xor(s1, m); }
    float mu0 = s0 * (1.f / DN), mu1 = s1 * (1.f / DN);

    float v0 = 0.f, v1 = 0.f;
#pragma unroll
    for (int c2 = 0; c2 < 16; ++c2) {
        float d0 = acc0[c2] - mu0; v0 += d0 * d0;
        float d1 = acc1[c2] - mu1; v1 += d1 * d1;
    }
#pragma unroll
    for (int m = 1; m < 16; m <<= 1) { v0 += __shfl_xor(v0, m); v1 += __shfl_xor(v1, m); }
    float is0 = rsqrtf(v0 * (1.f / DN) + LN_EPS);
    float is1 = rsqrtf(v1 * (1.f / DN) + LN_EPS);

    int row0 = n0 + 2 * ty, row1 = row0 + 1;
    if (row0 < N) {
#pragma unroll
        for (int c2 = 0; c2 < 16; ++c2) {
            float hn = (acc0[c2] - mu0) * is0 * gv[c2] + btv[c2];
            out[(size_t)row0 * DN + tx + 16 * c2] = hn / (1.f + expf(-hn));
        }
    }
    if (row1 < N) {
#pragma unroll
        for (int c2 = 0; c2 < 16; ++c2) {
            float hn = (acc1[c2] - mu1) * is1 * gv[c2] + btv[c2];
            out[(size_t)row1 * DN + tx + 16 * c2] = hn / (1.f + expf(-hn));
        }
    }
}

extern "C" void kernel_launch(void* const* d_in, const int* in_sizes, int n_in,
                              void* d_out, int out_size, void* d_ws, size_t ws_size,
                              hipStream_t stream) {
    const float* x  = (const float*)d_in[0];
    const int*   ei = (const int*)d_in[1];
    const float* W0 = (const float*)d_in[2];
    const float* b0 = (const float*)d_in[3];
    const float* g0 = (const float*)d_in[4];
    const float* be0 = (const float*)d_in[5];
    const float* W1 = (const float*)d_in[6];
    const float* b1 = (const float*)d_in[7];
    const float* g1 = (const float*)d_in[8];
    const float* be1 = (const float*)d_in[9];
    float* out = (float*)d_out;

    int N = in_sizes[0] / DN;
    int E = in_sizes[1] / 2;

    char* ws = (char*)d_ws;
    float* deg = (float*)ws;
    size_t deg_bytes = (((size_t)N * 4) + 255) & ~(size_t)255;
    float* agg = (float*)(ws + deg_bytes);

    int sblocks = (E + 3) / 4;              // one wave per edge, 4 waves/block
    int gblocks = (N + BM - 1) / BM;

    hipMemsetAsync(deg, 0, (size_t)N * 4, stream);
    hipMemsetAsync(agg, 0, (size_t)N * DN * 4, stream);
    deg_count<<<(E + 255) / 256, 256, 0, stream>>>(ei, deg, E);

    // layer 1
    scatter_add<<<sblocks, 256, 0, stream>>>(x, ei, agg, E);
    gemm_ln_silu<<<gblocks, 256, 0, stream>>>(x, agg, deg, W0, b0, g0, be0, out, N);

    // layer 2 (aggregate from layer-1 output; in-place GEMM is block-row-local safe)
    hipMemsetAsync(agg, 0, (size_t)N * DN * 4, stream);
    scatter_add<<<sblocks, 256, 0, stream>>>(out, ei, agg, E);
    gemm_ln_silu<<<gblocks, 256, 0, stream>>>(out, agg, deg, W1, b1, g1, be1, out, N);
}

// Round 2
// 1373.582 us; speedup vs baseline: 8.2903x; 8.2903x over previous
//
#include <hip/hip_runtime.h>
#include <math.h>

#define DN   256      // node/hidden dim
#define BM   32       // rows per GEMM block
#define BK   32       // k-tile
#define PADY 36
#define PADW 36
#define LN_EPS 1e-5f

// ---------------- CSR construction ----------------

__global__ __launch_bounds__(256) void deg_count(const int* __restrict__ ei,
                                                 int* __restrict__ deg, int E) {
    int e = blockIdx.x * 256 + threadIdx.x;
    if (e < E) atomicAdd(&deg[ei[e]], 1);
}

// single-block exclusive scan: rp[i] = sum(deg[0..i-1])
__global__ __launch_bounds__(256) void scan_deg(const int* __restrict__ deg,
                                                int* __restrict__ rp, int N) {
    __shared__ int wsum[4];
    __shared__ int carry_s;
    int tid = threadIdx.x;
    int lane = tid & 63, w = tid >> 6;
    if (tid == 0) carry_s = 0;
    __syncthreads();
    for (int base = 0; base < N; base += 256) {
        int i = base + tid;
        int v = (i < N) ? deg[i] : 0;
        int s = v;
#pragma unroll
        for (int m = 1; m < 64; m <<= 1) {
            int t = __shfl_up(s, m);
            if (lane >= m) s += t;
        }
        if (lane == 63) wsum[w] = s;
        __syncthreads();
        int woff = 0;
        for (int k = 0; k < w; ++k) woff += wsum[k];
        int carry = carry_s;
        __syncthreads();
        if (i < N) rp[i] = carry + woff + s - v;
        if (tid == 255) carry_s = carry + woff + s;
        __syncthreads();
    }
}

// fill CSR; mutates rp into end-pointers: rp[r] becomes end-of-row-r
__global__ __launch_bounds__(256) void csr_fill(const int* __restrict__ ei,
                                                int* __restrict__ rp,
                                                int* __restrict__ csr_col, int E) {
    int e = blockIdx.x * 256 + threadIdx.x;
    if (e < E) {
        int r = ei[e];
        int c = ei[E + e];
        int pos = atomicAdd(&rp[r], 1);
        csr_col[pos] = c;
    }
}

// ---------------- aggregation: y = x + mean(neighbors) ----------------
// one 64-lane wave per node; lane holds float4 (cols lane*4..lane*4+3)
__global__ __launch_bounds__(256) void aggregate(const float* __restrict__ x,
                                                 const int* __restrict__ rp_end,
                                                 const int* __restrict__ csr_col,
                                                 float* __restrict__ y, int N) {
    int wid  = (blockIdx.x * 256 + threadIdx.x) >> 6;
    int lane = threadIdx.x & 63;
    if (wid >= N) return;
    int start = (wid == 0) ? 0 : rp_end[wid - 1];
    int end   = rp_end[wid];

    float4 acc = make_float4(0.f, 0.f, 0.f, 0.f);
    int j = start;
    for (; j + 4 <= end; j += 4) {
        int c0 = csr_col[j], c1 = csr_col[j + 1], c2 = csr_col[j + 2], c3 = csr_col[j + 3];
        float4 v0 = reinterpret_cast<const float4*>(x + (size_t)c0 * DN)[lane];
        float4 v1 = reinterpret_cast<const float4*>(x + (size_t)c1 * DN)[lane];
        float4 v2 = reinterpret_cast<const float4*>(x + (size_t)c2 * DN)[lane];
        float4 v3 = reinterpret_cast<const float4*>(x + (size_t)c3 * DN)[lane];
        acc.x += v0.x + v1.x + v2.x + v3.x;
        acc.y += v0.y + v1.y + v2.y + v3.y;
        acc.z += v0.z + v1.z + v2.z + v3.z;
        acc.w += v0.w + v1.w + v2.w + v3.w;
    }
    for (; j < end; ++j) {
        int c = csr_col[j];
        float4 v = reinterpret_cast<const float4*>(x + (size_t)c * DN)[lane];
        acc.x += v.x; acc.y += v.y; acc.z += v.z; acc.w += v.w;
    }
    int deg = end - start;
    float inv = (deg > 0) ? 1.0f / (float)deg : 0.0f;
    float4 xv = reinterpret_cast<const float4*>(x + (size_t)wid * DN)[lane];
    float4 yv = make_float4(xv.x + acc.x * inv, xv.y + acc.y * inv,
                            xv.z + acc.z * inv, xv.w + acc.w * inv);
    reinterpret_cast<float4*>(y + (size_t)wid * DN)[lane] = yv;
}

// ---------------- fused GEMM + LayerNorm + SiLU ----------------
// h = y @ W^T + b; LN; SiLU. block: 256 threads, 32 rows x 256 cols.
__global__ __launch_bounds__(256) void gemm_ln_silu(
        const float* __restrict__ y, const float* __restrict__ W,
        const float* __restrict__ bias, const float* __restrict__ gam,
        const float* __restrict__ bet, float* __restrict__ out, int N) {
    __shared__ float y_lds[BM][PADY];
    __shared__ float w_lds[DN][PADW];

    int tid = threadIdx.x;
    int tx = tid & 15, ty = tid >> 4;
    int n0 = blockIdx.x * BM;

    float bv[16], gv[16], btv[16];
#pragma unroll
    for (int c2 = 0; c2 < 16; ++c2) {
        int jj = tx + 16 * c2;
        bv[c2]  = bias[jj];
        gv[c2]  = gam[jj];
        btv[c2] = bet[jj];
    }
    float acc0[16], acc1[16];
#pragma unroll
    for (int c2 = 0; c2 < 16; ++c2) { acc0[c2] = 0.f; acc1[c2] = 0.f; }

    int sr = tid >> 3;           // staging row 0..31
    int sq = (tid & 7) * 4;      // staging float4 offset within k-tile

    for (int kt = 0; kt < DN / BK; ++kt) {
        int k0 = kt * BK;
        __syncthreads();
#pragma unroll
        for (int i = 0; i < 8; ++i) {
            int jj = i * 32 + (tid >> 3);
            float4 wv = *reinterpret_cast<const float4*>(&W[(size_t)jj * DN + k0 + sq]);
            *reinterpret_cast<float4*>(&w_lds[jj][sq]) = wv;
        }
        {
            int n = n0 + sr;
            float4 yv = make_float4(0.f, 0.f, 0.f, 0.f);
            if (n < N)
                yv = *reinterpret_cast<const float4*>(&y[(size_t)n * DN + k0 + sq]);
            *reinterpret_cast<float4*>(&y_lds[sr][sq]) = yv;
        }
        __syncthreads();
#pragma unroll
        for (int q = 0; q < 8; ++q) {
            float4 y0 = *reinterpret_cast<const float4*>(&y_lds[2 * ty + 0][4 * q]);
            float4 y1 = *reinterpret_cast<const float4*>(&y_lds[2 * ty + 1][4 * q]);
#pragma unroll
            for (int c2 = 0; c2 < 16; ++c2) {
                float4 wv = *reinterpret_cast<const float4*>(&w_lds[tx + 16 * c2][4 * q]);
                acc0[c2] += y0.x * wv.x + y0.y * wv.y + y0.z * wv.z + y0.w * wv.w;
                acc1[c2] += y1.x * wv.x + y1.y * wv.y + y1.z * wv.z + y1.w * wv.w;
            }
        }
    }

#pragma unroll
    for (int c2 = 0; c2 < 16; ++c2) { acc0[c2] += bv[c2]; acc1[c2] += bv[c2]; }

    float s0 = 0.f, s1 = 0.f;
#pragma unroll
    for (int c2 = 0; c2 < 16; ++c2) { s0 += acc0[c2]; s1 += acc1[c2]; }
#pragma unroll
    for (int m = 1; m < 16; m <<= 1) { s0 += __shfl_xor(s0, m); s1 += __shfl_xor(s1, m); }
    float mu0 = s0 * (1.f / DN), mu1 = s1 * (1.f / DN);

    float v0 = 0.f, v1 = 0.f;
#pragma unroll
    for (int c2 = 0; c2 < 16; ++c2) {
        float d0 = acc0[c2] - mu0; v0 += d0 * d0;
        float d1 = acc1[c2] - mu1; v1 += d1 * d1;
    }
#pragma unroll
    for (int m = 1; m < 16; m <<= 1) { v0 += __shfl_xor(v0, m); v1 += __shfl_xor(v1, m); }
    float is0 = rsqrtf(v0 * (1.f / DN) + LN_EPS);
    float is1 = rsqrtf(v1 * (1.f / DN) + LN_EPS);

    int row0 = n0 + 2 * ty, row1 = row0 + 1;
    if (row0 < N) {
#pragma unroll
        for (int c2 = 0; c2 < 16; ++c2) {
            float hn = (acc0[c2] - mu0) * is0 * gv[c2] + btv[c2];
            out[(size_t)row0 * DN + tx + 16 * c2] = hn / (1.f + expf(-hn));
        }
    }
    if (row1 < N) {
#pragma unroll
        for (int c2 = 0; c2 < 16; ++c2) {
            float hn = (acc1[c2] - mu1) * is1 * gv[c2] + btv[c2];
            out[(size_t)row1 * DN + tx + 16 * c2] = hn / (1.f + expf(-hn));
        }
    }
}

extern "C" void kernel_launch(void* const* d_in, const int* in_sizes, int n_in,
                              void* d_out, int out_size, void* d_ws, size_t ws_size,
                              hipStream_t stream) {
    const float* x  = (const float*)d_in[0];
    const int*   ei = (const int*)d_in[1];
    const float* W0 = (const float*)d_in[2];
    const float* b0 = (const float*)d_in[3];
    const float* g0 = (const float*)d_in[4];
    const float* be0 = (const float*)d_in[5];
    const float* W1 = (const float*)d_in[6];
    const float* b1 = (const float*)d_in[7];
    const float* g1 = (const float*)d_in[8];
    const float* be1 = (const float*)d_in[9];
    float* out = (float*)d_out;

    int N = in_sizes[0] / DN;
    int E = in_sizes[1] / 2;

    // workspace layout
    char* ws = (char*)d_ws;
    size_t off = 0;
    int* deg_i = (int*)(ws + off);  off += (((size_t)N * 4) + 255) & ~(size_t)255;
    int* rp    = (int*)(ws + off);  off += (((size_t)N * 4) + 255) & ~(size_t)255;
    int* csr_c = (int*)(ws + off);  off += (((size_t)E * 4) + 255) & ~(size_t)255;
    float* ybuf = (float*)(ws + off);

    int eblocks = (E + 255) / 256;
    int ablocks = (N + 3) / 4;               // one wave per node, 4 waves/block
    int gblocks = (N + BM - 1) / BM;

    // CSR build (per call; rp is recomputed from scratch each call)
    hipMemsetAsync(deg_i, 0, (size_t)N * 4, stream);
    deg_count<<<eblocks, 256, 0, stream>>>(ei, deg_i, E);
    scan_deg<<<1, 256, 0, stream>>>(deg_i, rp, N);
    csr_fill<<<eblocks, 256, 0, stream>>>(ei, rp, csr_c, E);  // rp -> end pointers

    // layer 1
    aggregate<<<ablocks, 256, 0, stream>>>(x, rp, csr_c, ybuf, N);
    gemm_ln_silu<<<gblocks, 256, 0, stream>>>(ybuf, W0, b0, g0, be0, out, N);

    // layer 2
    aggregate<<<ablocks, 256, 0, stream>>>(out, rp, csr_c, ybuf, N);
    gemm_ln_silu<<<gblocks, 256, 0, stream>>>(ybuf, W1, b1, g1, be1, out, N);
}

// Round 4
// 911.893 us; speedup vs baseline: 12.4877x; 1.5063x over previous
//
#include <hip/hip_runtime.h>
#include <math.h>

#define DN 256
#define LN_EPS 1e-5f

using f32x4  = __attribute__((ext_vector_type(4))) float;
using short8 = __attribute__((ext_vector_type(8))) short;

__device__ __forceinline__ ushort f2bf(float f) {
    uint u = __float_as_uint(f);
    u += 0x7fff + ((u >> 16) & 1);           // round-to-nearest-even
    return (ushort)(u >> 16);
}
__device__ __forceinline__ float bf2f(ushort h) { return __uint_as_float((uint)h << 16); }

// ---------------- W split cast: f32 -> bf16 hi + bf16 lo ----------------
__global__ __launch_bounds__(256) void cast_split(const float* __restrict__ src,
                                                  ushort* __restrict__ hi,
                                                  ushort* __restrict__ lo, int n4) {
    int i = blockIdx.x * 256 + threadIdx.x;
    if (i >= n4) return;
    float4 a = reinterpret_cast<const float4*>(src)[i];
    ushort h0 = f2bf(a.x), h1 = f2bf(a.y), h2 = f2bf(a.z), h3 = f2bf(a.w);
    uint2 ho, lu;
    ho.x = (uint)h0 | ((uint)h1 << 16);
    ho.y = (uint)h2 | ((uint)h3 << 16);
    lu.x = (uint)f2bf(a.x - bf2f(h0)) | ((uint)f2bf(a.y - bf2f(h1)) << 16);
    lu.y = (uint)f2bf(a.z - bf2f(h2)) | ((uint)f2bf(a.w - bf2f(h3)) << 16);
    reinterpret_cast<uint2*>(hi)[i] = ho;
    reinterpret_cast<uint2*>(lo)[i] = lu;
}

// ---------------- CSR construction ----------------
__global__ __launch_bounds__(256) void deg_count(const int* __restrict__ ei,
                                                 int* __restrict__ rp, int E) {
    int e = blockIdx.x * 256 + threadIdx.x;
    if (e < E) atomicAdd(&rp[ei[e]], 1);
}

// 3-phase parallel exclusive scan of rp[0..N) (in place), nblk <= 256
__global__ __launch_bounds__(256) void scan_phase1(int* __restrict__ rp,
                                                   int* __restrict__ part, int N) {
    __shared__ int wsum[4];
    int tid = threadIdx.x, lane = tid & 63, w = tid >> 6;
    int i = blockIdx.x * 256 + tid;
    int v = (i < N) ? rp[i] : 0;
    int s = v;
#pragma unroll
    for (int m = 1; m < 64; m <<= 1) {
        int t = __shfl_up(s, m);
        if (lane >= m) s += t;
    }
    if (lane == 63) wsum[w] = s;
    __syncthreads();
    int woff = 0;
    for (int k = 0; k < w; ++k) woff += wsum[k];
    if (i < N) rp[i] = woff + s - v;
    if (tid == 255) part[blockIdx.x] = woff + s;
}

__global__ __launch_bounds__(256) void scan_phase2(int* __restrict__ part, int nblk) {
    __shared__ int wsum[4];
    int tid = threadIdx.x, lane = tid & 63, w = tid >> 6;
    int v = (tid < nblk) ? part[tid] : 0;
    int s = v;
#pragma unroll
    for (int m = 1; m < 64; m <<= 1) {
        int t = __shfl_up(s, m);
        if (lane >= m) s += t;
    }
    if (lane == 63) wsum[w] = s;
    __syncthreads();
    int woff = 0;
    for (int k = 0; k < w; ++k) woff += wsum[k];
    if (tid < nblk) part[tid] = woff + s - v;
}

__global__ __launch_bounds__(256) void scan_phase3(int* __restrict__ rp,
                                                   const int* __restrict__ part, int N) {
    int i = blockIdx.x * 256 + threadIdx.x;
    if (i < N) rp[i] += part[blockIdx.x];
}

// fill CSR; mutates rp into end-pointers
__global__ __launch_bounds__(256) void csr_fill(const int* __restrict__ ei,
                                                int* __restrict__ rp,
                                                int* __restrict__ csr_col, int E) {
    int e = blockIdx.x * 256 + threadIdx.x;
    if (e < E) {
        int pos = atomicAdd(&rp[ei[e]], 1);
        csr_col[pos] = ei[E + e];
    }
}

// ---------------- aggregation: y = self + mean(neighbors) ----------------
// fp32 in, split bf16 (hi, lo) out. one 64-lane wave per node.
__global__ __launch_bounds__(256) void aggregate_split(const float* __restrict__ xf,
                                                       const int* __restrict__ rp_end,
                                                       const int* __restrict__ csr_col,
                                                       ushort* __restrict__ yhi,
                                                       ushort* __restrict__ ylo, int N) {
    int wid  = (blockIdx.x * 256 + threadIdx.x) >> 6;
    int lane = threadIdx.x & 63;
    if (wid >= N) return;
    int start = (wid == 0) ? 0 : rp_end[wid - 1];
    int end   = rp_end[wid];

    float a0 = 0.f, a1 = 0.f, a2 = 0.f, a3 = 0.f;
    int j = start;
    for (; j + 4 <= end; j += 4) {
        int c0 = csr_col[j], c1 = csr_col[j + 1], c2 = csr_col[j + 2], c3 = csr_col[j + 3];
        float4 v0 = reinterpret_cast<const float4*>(xf + (size_t)c0 * DN)[lane];
        float4 v1 = reinterpret_cast<const float4*>(xf + (size_t)c1 * DN)[lane];
        float4 v2 = reinterpret_cast<const float4*>(xf + (size_t)c2 * DN)[lane];
        float4 v3 = reinterpret_cast<const float4*>(xf + (size_t)c3 * DN)[lane];
        a0 += v0.x + v1.x + v2.x + v3.x;
        a1 += v0.y + v1.y + v2.y + v3.y;
        a2 += v0.z + v1.z + v2.z + v3.z;
        a3 += v0.w + v1.w + v2.w + v3.w;
    }
    for (; j < end; ++j) {
        int c = csr_col[j];
        float4 v = reinterpret_cast<const float4*>(xf + (size_t)c * DN)[lane];
        a0 += v.x; a1 += v.y; a2 += v.z; a3 += v.w;
    }
    int deg = end - start;
    float inv = (deg > 0) ? 1.0f / (float)deg : 0.0f;
    float4 xv = reinterpret_cast<const float4*>(xf + (size_t)wid * DN)[lane];
    float y0 = xv.x + a0 * inv, y1 = xv.y + a1 * inv;
    float y2 = xv.z + a2 * inv, y3 = xv.w + a3 * inv;
    ushort h0 = f2bf(y0), h1 = f2bf(y1), h2 = f2bf(y2), h3 = f2bf(y3);
    uint2 ho, lu;
    ho.x = (uint)h0 | ((uint)h1 << 16);
    ho.y = (uint)h2 | ((uint)h3 << 16);
    lu.x = (uint)f2bf(y0 - bf2f(h0)) | ((uint)f2bf(y1 - bf2f(h1)) << 16);
    lu.y = (uint)f2bf(y2 - bf2f(h2)) | ((uint)f2bf(y3 - bf2f(h3)) << 16);
    *reinterpret_cast<uint2*>(yhi + (size_t)wid * DN + lane * 4) = ho;
    *reinterpret_cast<uint2*>(ylo + (size_t)wid * DN + lane * 4) = lu;
}

// ---------------- split-precision MFMA GEMM + LayerNorm + SiLU ----------------
// h = (yhi+ylo) @ (Whi+Wlo)^T + b, dropping only the ylo*Wlo (eps^2) term.
// block = 4 waves; wave w owns rows n0+w*16..+15, all 256 cols.
// 4 LDS stages of 64KB: Whi[k 0:128], Whi[k 128:256], Wlo[k 0:128], Wlo[k 128:256].
__global__ __launch_bounds__(256) void gemm_ln_silu_mfma(
        const ushort* __restrict__ yhi, const ushort* __restrict__ ylo,
        const ushort* __restrict__ whi, const ushort* __restrict__ wlo,
        const float* __restrict__ bias, const float* __restrict__ gam,
        const float* __restrict__ bet, float* __restrict__ out, int N) {
    __shared__ uint4 wl4[4096];                 // 64 KB
    char* wl = (char*)wl4;

    int tid = threadIdx.x;
    int w = tid >> 6, lane = tid & 63;
    int g = lane >> 4, c0 = lane & 15;
    int n0 = blockIdx.x * 64;

    // prefetch all A-frags (K=256 -> 8 k-steps of 32), hi and lo
    int arow = n0 + w * 16 + c0;
    bool av = arow < N;
    const ushort* ah = yhi + (size_t)arow * DN + g * 8;
    const ushort* al = ylo + (size_t)arow * DN + g * 8;
    short8 zz = {0, 0, 0, 0, 0, 0, 0, 0};
    short8 ahi[8], alo[8];
#pragma unroll
    for (int kk = 0; kk < 8; ++kk) {
        ahi[kk] = av ? *reinterpret_cast<const short8*>(ah + kk * 32) : zz;
        alo[kk] = av ? *reinterpret_cast<const short8*>(al + kk * 32) : zz;
    }

    f32x4 acc[16];
#pragma unroll
    for (int t = 0; t < 16; ++t) acc[t] = (f32x4){0.f, 0.f, 0.f, 0.f};

#pragma unroll
    for (int st = 0; st < 4; ++st) {
        const ushort* wsrc = (st < 2) ? whi : wlo;
        int h = st & 1;
        __syncthreads();
        // stage wsrc[:, h*128 .. h*128+127] -> 64 KB LDS, XOR-swizzled
#pragma unroll
        for (int i = 0; i < 16; ++i) {
            int chunk = tid + 256 * i;          // 0..4095 16B chunks
            int j = chunk >> 4;                 // W row (= output col)
            int kb16 = chunk & 15;              // 16B unit within 256B half-row
            uint4 val = *reinterpret_cast<const uint4*>(wsrc + (size_t)j * DN + h * 128 + kb16 * 8);
            int dst = (j * 256 + kb16 * 16) ^ ((j & 7) << 4);
            *reinterpret_cast<uint4*>(wl + dst) = val;
        }
        __syncthreads();
#pragma unroll
        for (int kk4 = 0; kk4 < 4; ++kk4) {
            int kk = h * 4 + kk4;
            int kb = (kk4 * 32 + g * 8) * 2;    // byte offset within half-row
#pragma unroll
            for (int t = 0; t < 16; ++t) {
                int j = t * 16 + c0;
                int addr = (j * 256 + kb) ^ ((j & 7) << 4);
                short8 bfr = *reinterpret_cast<const short8*>(wl + addr);
                acc[t] = __builtin_amdgcn_mfma_f32_16x16x32_bf16(ahi[kk], bfr, acc[t], 0, 0, 0);
                if (st < 2)
                    acc[t] = __builtin_amdgcn_mfma_f32_16x16x32_bf16(alo[kk], bfr, acc[t], 0, 0, 0);
            }
        }
    }

    // epilogue: bias + LayerNorm + SiLU (fp32)
#pragma unroll
    for (int t = 0; t < 16; ++t) {
        float bb = bias[t * 16 + c0];
#pragma unroll
        for (int r = 0; r < 4; ++r) acc[t][r] += bb;
    }

    float s[4] = {0.f, 0.f, 0.f, 0.f};
#pragma unroll
    for (int t = 0; t < 16; ++t)
#pragma unroll
        for (int r = 0; r < 4; ++r) s[r] += acc[t][r];
#pragma unroll
    for (int r = 0; r < 4; ++r) {
#pragma unroll
        for (int m = 1; m < 16; m <<= 1) s[r] += __shfl_xor(s[r], m);
        s[r] *= (1.f / DN);                     // mu
    }
    float vv[4] = {0.f, 0.f, 0.f, 0.f};
#pragma unroll
    for (int t = 0; t < 16; ++t)
#pragma unroll
        for (int r = 0; r < 4; ++r) { float d = acc[t][r] - s[r]; vv[r] += d * d; }
#pragma unroll
    for (int r = 0; r < 4; ++r) {
#pragma unroll
        for (int m = 1; m < 16; m <<= 1) vv[r] += __shfl_xor(vv[r], m);
        vv[r] = rsqrtf(vv[r] * (1.f / DN) + LN_EPS);
    }

    float gvv[16], btt[16];
#pragma unroll
    for (int t = 0; t < 16; ++t) {
        gvv[t] = gam[t * 16 + c0];
        btt[t] = bet[t * 16 + c0];
    }
#pragma unroll
    for (int r = 0; r < 4; ++r) {
        int row = n0 + w * 16 + g * 4 + r;
        if (row >= N) continue;
#pragma unroll
        for (int t = 0; t < 16; ++t) {
            float hn = (acc[t][r] - s[r]) * vv[r] * gvv[t] + btt[t];
            out[(size_t)row * DN + t * 16 + c0] = hn / (1.f + __expf(-hn));
        }
    }
}

extern "C" void kernel_launch(void* const* d_in, const int* in_sizes, int n_in,
                              void* d_out, int out_size, void* d_ws, size_t ws_size,
                              hipStream_t stream) {
    const float* x  = (const float*)d_in[0];
    const int*   ei = (const int*)d_in[1];
    const float* W0 = (const float*)d_in[2];
    const float* b0 = (const float*)d_in[3];
    const float* g0 = (const float*)d_in[4];
    const float* be0 = (const float*)d_in[5];
    const float* W1 = (const float*)d_in[6];
    const float* b1 = (const float*)d_in[7];
    const float* g1 = (const float*)d_in[8];
    const float* be1 = (const float*)d_in[9];
    float* out = (float*)d_out;

    int N = in_sizes[0] / DN;
    int E = in_sizes[1] / 2;

    // workspace: rp | part | csr | yhi | ylo | whi0 | wlo0 | whi1 | wlo1
    // h1 (fp32) lives in d_out between gemm1 and gemm2.
    char* ws = (char*)d_ws;
    size_t off = 0;
    auto alloc = [&](size_t bytes) { void* p = ws + off;
                                     off = (off + bytes + 255) & ~(size_t)255; return p; };
    int* rp     = (int*)alloc((size_t)N * 4);
    int* part   = (int*)alloc(256 * 4);
    int* csr_c  = (int*)alloc((size_t)E * 4);
    ushort* yhi = (ushort*)alloc((size_t)N * DN * 2);
    ushort* ylo = (ushort*)alloc((size_t)N * DN * 2);
    ushort* whi0 = (ushort*)alloc((size_t)DN * DN * 2);
    ushort* wlo0 = (ushort*)alloc((size_t)DN * DN * 2);
    ushort* whi1 = (ushort*)alloc((size_t)DN * DN * 2);
    ushort* wlo1 = (ushort*)alloc((size_t)DN * DN * 2);

    int eblocks = (E + 255) / 256;
    int nblocks = (N + 255) / 256;   // 196 <= 256 (scan_phase2 capacity)
    int ablocks = (N + 3) / 4;
    int gblocks = (N + 63) / 64;

    // CSR build
    hipMemsetAsync(rp, 0, (size_t)N * 4, stream);
    deg_count<<<eblocks, 256, 0, stream>>>(ei, rp, E);
    scan_phase1<<<nblocks, 256, 0, stream>>>(rp, part, N);
    scan_phase2<<<1, 256, 0, stream>>>(part, nblocks);
    scan_phase3<<<nblocks, 256, 0, stream>>>(rp, part, N);
    csr_fill<<<eblocks, 256, 0, stream>>>(ei, rp, csr_c, E);

    // W splits
    cast_split<<<(DN * DN / 4 + 255) / 256, 256, 0, stream>>>(W0, whi0, wlo0, DN * DN / 4);
    cast_split<<<(DN * DN / 4 + 255) / 256, 256, 0, stream>>>(W1, whi1, wlo1, DN * DN / 4);

    // layer 1: aggregate fp32 x -> (yhi,ylo); GEMM -> h1 (fp32) in d_out
    aggregate_split<<<ablocks, 256, 0, stream>>>(x, rp, csr_c, yhi, ylo, N);
    gemm_ln_silu_mfma<<<gblocks, 256, 0, stream>>>(yhi, ylo, whi0, wlo0,
                                                   b0, g0, be0, out, N);
    // layer 2: aggregate fp32 h1 -> (yhi,ylo); GEMM overwrites d_out with final
    aggregate_split<<<ablocks, 256, 0, stream>>>(out, rp, csr_c, yhi, ylo, N);
    gemm_ln_silu_mfma<<<gblocks, 256, 0, stream>>>(yhi, ylo, whi1, wlo1,
                                                   b1, g1, be1, out, N);
}

// Round 5
// 707.647 us; speedup vs baseline: 16.0920x; 1.2886x over previous
//
#include <hip/hip_runtime.h>
#include <math.h>

#define DN 256
#define LN_EPS 1e-5f

using f32x4  = __attribute__((ext_vector_type(4))) float;
using short8 = __attribute__((ext_vector_type(8))) short;

__device__ __forceinline__ ushort f2bf(float f) {
    uint u = __float_as_uint(f);
    u += 0x7fff + ((u >> 16) & 1);           // round-to-nearest-even
    return (ushort)(u >> 16);
}
__device__ __forceinline__ float bf2f(ushort h) { return __uint_as_float((uint)h << 16); }
__device__ __forceinline__ float bf_lo(uint u) { return __uint_as_float(u << 16); }
__device__ __forceinline__ float bf_hi(uint u) { return __uint_as_float(u & 0xffff0000u); }

// ---------------- x -> bf16 cast (neighbor-gather source) ----------------
__global__ __launch_bounds__(256) void cast_f32_bf16(const float* __restrict__ src,
                                                     ushort* __restrict__ dst, int n8) {
    int i = blockIdx.x * 256 + threadIdx.x;
    if (i >= n8) return;
    float4 a = reinterpret_cast<const float4*>(src)[2 * i];
    float4 b = reinterpret_cast<const float4*>(src)[2 * i + 1];
    uint4 o;
    o.x = (uint)f2bf(a.x) | ((uint)f2bf(a.y) << 16);
    o.y = (uint)f2bf(a.z) | ((uint)f2bf(a.w) << 16);
    o.z = (uint)f2bf(b.x) | ((uint)f2bf(b.y) << 16);
    o.w = (uint)f2bf(b.z) | ((uint)f2bf(b.w) << 16);
    reinterpret_cast<uint4*>(dst)[i] = o;
}

// ---------------- W split cast: f32 -> bf16 hi + bf16 lo ----------------
__global__ __launch_bounds__(256) void cast_split(const float* __restrict__ src,
                                                  ushort* __restrict__ hi,
                                                  ushort* __restrict__ lo, int n4) {
    int i = blockIdx.x * 256 + threadIdx.x;
    if (i >= n4) return;
    float4 a = reinterpret_cast<const float4*>(src)[i];
    ushort h0 = f2bf(a.x), h1 = f2bf(a.y), h2 = f2bf(a.z), h3 = f2bf(a.w);
    uint2 ho, lu;
    ho.x = (uint)h0 | ((uint)h1 << 16);
    ho.y = (uint)h2 | ((uint)h3 << 16);
    lu.x = (uint)f2bf(a.x - bf2f(h0)) | ((uint)f2bf(a.y - bf2f(h1)) << 16);
    lu.y = (uint)f2bf(a.z - bf2f(h2)) | ((uint)f2bf(a.w - bf2f(h3)) << 16);
    reinterpret_cast<uint2*>(hi)[i] = ho;
    reinterpret_cast<uint2*>(lo)[i] = lu;
}

// ---------------- CSR construction ----------------
__global__ __launch_bounds__(256) void deg_count(const int* __restrict__ ei,
                                                 int* __restrict__ rp, int E) {
    int e = blockIdx.x * 256 + threadIdx.x;
    if (e < E) atomicAdd(&rp[ei[e]], 1);
}

__global__ __launch_bounds__(256) void scan_phase1(int* __restrict__ rp,
                                                   int* __restrict__ part, int N) {
    __shared__ int wsum[4];
    int tid = threadIdx.x, lane = tid & 63, w = tid >> 6;
    int i = blockIdx.x * 256 + tid;
    int v = (i < N) ? rp[i] : 0;
    int s = v;
#pragma unroll
    for (int m = 1; m < 64; m <<= 1) {
        int t = __shfl_up(s, m);
        if (lane >= m) s += t;
    }
    if (lane == 63) wsum[w] = s;
    __syncthreads();
    int woff = 0;
    for (int k = 0; k < w; ++k) woff += wsum[k];
    if (i < N) rp[i] = woff + s - v;
    if (tid == 255) part[blockIdx.x] = woff + s;
}

__global__ __launch_bounds__(256) void scan_phase2(int* __restrict__ part, int nblk) {
    __shared__ int wsum[4];
    int tid = threadIdx.x, lane = tid & 63, w = tid >> 6;
    int v = (tid < nblk) ? part[tid] : 0;
    int s = v;
#pragma unroll
    for (int m = 1; m < 64; m <<= 1) {
        int t = __shfl_up(s, m);
        if (lane >= m) s += t;
    }
    if (lane == 63) wsum[w] = s;
    __syncthreads();
    int woff = 0;
    for (int k = 0; k < w; ++k) woff += wsum[k];
    if (tid < nblk) part[tid] = woff + s - v;
}

__global__ __launch_bounds__(256) void scan_phase3(int* __restrict__ rp,
                                                   const int* __restrict__ part, int N) {
    int i = blockIdx.x * 256 + threadIdx.x;
    if (i < N) rp[i] += part[blockIdx.x];
}

__global__ __launch_bounds__(256) void csr_fill(const int* __restrict__ ei,
                                                int* __restrict__ rp,
                                                int* __restrict__ csr_col, int E) {
    int e = blockIdx.x * 256 + threadIdx.x;
    if (e < E) {
        int pos = atomicAdd(&rp[ei[e]], 1);
        csr_col[pos] = ei[E + e];
    }
}

// ---------------- aggregation: y = self(fp32) + mean(neighbors bf16) ----------------
// writes y as split bf16 PACKED per row: [256 x hi][256 x lo] (1024B = fp32 row size).
// out_packed may alias xf_self (read-before-write within the owning wave only).
__global__ __launch_bounds__(256) void aggregate_packed(const float* xf_self,
                                                        const ushort* __restrict__ xb_neigh,
                                                        const int* __restrict__ rp_end,
                                                        const int* __restrict__ csr_col,
                                                        ushort* out_packed, int N) {
    int wid  = (blockIdx.x * 256 + threadIdx.x) >> 6;
    int lane = threadIdx.x & 63;
    if (wid >= N) return;
    int start = (wid == 0) ? 0 : rp_end[wid - 1];
    int end   = rp_end[wid];

    // self row (fp32) first — must complete before the packed write (may alias)
    float4 xv = reinterpret_cast<const float4*>(xf_self + (size_t)wid * DN)[lane];

    float a0 = 0.f, a1 = 0.f, a2 = 0.f, a3 = 0.f;
    int j = start;
    for (; j + 8 <= end; j += 8) {
        uint2 v[8];
#pragma unroll
        for (int q = 0; q < 8; ++q) {
            int c = csr_col[j + q];
            v[q] = *reinterpret_cast<const uint2*>(xb_neigh + (size_t)c * DN + lane * 4);
        }
#pragma unroll
        for (int q = 0; q < 8; ++q) {
            a0 += bf_lo(v[q].x); a1 += bf_hi(v[q].x);
            a2 += bf_lo(v[q].y); a3 += bf_hi(v[q].y);
        }
    }
    for (; j < end; ++j) {
        int c = csr_col[j];
        uint2 v = *reinterpret_cast<const uint2*>(xb_neigh + (size_t)c * DN + lane * 4);
        a0 += bf_lo(v.x); a1 += bf_hi(v.x); a2 += bf_lo(v.y); a3 += bf_hi(v.y);
    }
    int deg = end - start;
    float inv = (deg > 0) ? 1.0f / (float)deg : 0.0f;
    float y0 = xv.x + a0 * inv, y1 = xv.y + a1 * inv;
    float y2 = xv.z + a2 * inv, y3 = xv.w + a3 * inv;
    ushort h0 = f2bf(y0), h1 = f2bf(y1), h2 = f2bf(y2), h3 = f2bf(y3);
    uint2 ho, lu;
    ho.x = (uint)h0 | ((uint)h1 << 16);
    ho.y = (uint)h2 | ((uint)h3 << 16);
    lu.x = (uint)f2bf(y0 - bf2f(h0)) | ((uint)f2bf(y1 - bf2f(h1)) << 16);
    lu.y = (uint)f2bf(y2 - bf2f(h2)) | ((uint)f2bf(y3 - bf2f(h3)) << 16);
    ushort* row = out_packed + (size_t)wid * 512;
    *reinterpret_cast<uint2*>(row + lane * 4) = ho;          // hi section [0,256)
    *reinterpret_cast<uint2*>(row + 256 + lane * 4) = lu;    // lo section [256,512)
}

// ---------------- split-precision MFMA GEMM + LayerNorm + SiLU ----------------
// A from packed split rows (row stride 512 ushorts: hi | lo). In-place: outf may
// alias yb (A-frags fully prefetched before epilogue stores; rows block-local).
__global__ __launch_bounds__(256) void gemm_ln_silu_mfma(
        const ushort* yb, const ushort* __restrict__ whi, const ushort* __restrict__ wlo,
        const float* __restrict__ bias, const float* __restrict__ gam,
        const float* __restrict__ bet,
        float* outf, ushort* __restrict__ outb, int N) {
    __shared__ uint4 wl4[4096];                 // 64 KB
    char* wl = (char*)wl4;

    int tid = threadIdx.x;
    int w = tid >> 6, lane = tid & 63;
    int g = lane >> 4, c0 = lane & 15;
    int n0 = blockIdx.x * 64;

    // prefetch all A-frags (K=256 -> 8 k-steps of 32), hi and lo, packed layout
    int arow = n0 + w * 16 + c0;
    bool av = arow < N;
    const ushort* ah = yb + (size_t)arow * 512 + g * 8;
    short8 zz = {0, 0, 0, 0, 0, 0, 0, 0};
    short8 ahi[8], alo[8];
#pragma unroll
    for (int kk = 0; kk < 8; ++kk) {
        ahi[kk] = av ? *reinterpret_cast<const short8*>(ah + kk * 32) : zz;
        alo[kk] = av ? *reinterpret_cast<const short8*>(ah + 256 + kk * 32) : zz;
    }

    f32x4 acc[16];
#pragma unroll
    for (int t = 0; t < 16; ++t) acc[t] = (f32x4){0.f, 0.f, 0.f, 0.f};

#pragma unroll
    for (int st = 0; st < 4; ++st) {
        const ushort* wsrc = (st < 2) ? whi : wlo;
        int h = st & 1;
        __syncthreads();
        // stage wsrc[:, h*128 .. h*128+127] -> 64 KB LDS, XOR-swizzled
#pragma unroll
        for (int i = 0; i < 16; ++i) {
            int chunk = tid + 256 * i;          // 0..4095 16B chunks
            int j = chunk >> 4;                 // W row (= output col)
            int kb16 = chunk & 15;              // 16B unit within 256B half-row
            uint4 val = *reinterpret_cast<const uint4*>(wsrc + (size_t)j * DN + h * 128 + kb16 * 8);
            int dst = (j * 256 + kb16 * 16) ^ ((j & 7) << 4);
            *reinterpret_cast<uint4*>(wl + dst) = val;
        }
        __syncthreads();
#pragma unroll
        for (int kk4 = 0; kk4 < 4; ++kk4) {
            int kk = h * 4 + kk4;
            int kb = (kk4 * 32 + g * 8) * 2;    // byte offset within half-row
#pragma unroll
            for (int t = 0; t < 16; ++t) {
                int j = t * 16 + c0;
                int addr = (j * 256 + kb) ^ ((j & 7) << 4);
                short8 bfr = *reinterpret_cast<const short8*>(wl + addr);
                acc[t] = __builtin_amdgcn_mfma_f32_16x16x32_bf16(ahi[kk], bfr, acc[t], 0, 0, 0);
                if (st < 2)
                    acc[t] = __builtin_amdgcn_mfma_f32_16x16x32_bf16(alo[kk], bfr, acc[t], 0, 0, 0);
            }
        }
    }

    // epilogue: bias + LayerNorm + SiLU (fp32)
#pragma unroll
    for (int t = 0; t < 16; ++t) {
        float bb = bias[t * 16 + c0];
#pragma unroll
        for (int r = 0; r < 4; ++r) acc[t][r] += bb;
    }

    float s[4] = {0.f, 0.f, 0.f, 0.f};
#pragma unroll
    for (int t = 0; t < 16; ++t)
#pragma unroll
        for (int r = 0; r < 4; ++r) s[r] += acc[t][r];
#pragma unroll
    for (int r = 0; r < 4; ++r) {
#pragma unroll
        for (int m = 1; m < 16; m <<= 1) s[r] += __shfl_xor(s[r], m);
        s[r] *= (1.f / DN);                     // mu
    }
    float vv[4] = {0.f, 0.f, 0.f, 0.f};
#pragma unroll
    for (int t = 0; t < 16; ++t)
#pragma unroll
        for (int r = 0; r < 4; ++r) { float d = acc[t][r] - s[r]; vv[r] += d * d; }
#pragma unroll
    for (int r = 0; r < 4; ++r) {
#pragma unroll
        for (int m = 1; m < 16; m <<= 1) vv[r] += __shfl_xor(vv[r], m);
        vv[r] = rsqrtf(vv[r] * (1.f / DN) + LN_EPS);
    }

    float gvv[16], btt[16];
#pragma unroll
    for (int t = 0; t < 16; ++t) {
        gvv[t] = gam[t * 16 + c0];
        btt[t] = bet[t * 16 + c0];
    }
#pragma unroll
    for (int r = 0; r < 4; ++r) {
        int row = n0 + w * 16 + g * 4 + r;
        if (row >= N) continue;
#pragma unroll
        for (int t = 0; t < 16; ++t) {
            float hn = (acc[t][r] - s[r]) * vv[r] * gvv[t] + btt[t];
            float sil = hn / (1.f + __expf(-hn));
            size_t o = (size_t)row * DN + t * 16 + c0;
            outf[o] = sil;
            if (outb) outb[o] = f2bf(sil);
        }
    }
}

extern "C" void kernel_launch(void* const* d_in, const int* in_sizes, int n_in,
                              void* d_out, int out_size, void* d_ws, size_t ws_size,
                              hipStream_t stream) {
    const float* x  = (const float*)d_in[0];
    const int*   ei = (const int*)d_in[1];
    const float* W0 = (const float*)d_in[2];
    const float* b0 = (const float*)d_in[3];
    const float* g0 = (const float*)d_in[4];
    const float* be0 = (const float*)d_in[5];
    const float* W1 = (const float*)d_in[6];
    const float* b1 = (const float*)d_in[7];
    const float* g1 = (const float*)d_in[8];
    const float* be1 = (const float*)d_in[9];
    float* out = (float*)d_out;
    ushort* outp = (ushort*)d_out;              // packed split-y view of d_out

    int N = in_sizes[0] / DN;
    int E = in_sizes[1] / 2;

    // workspace: rp | part | csr | xb (x bf16, later h1 bf16) | W splits  (~33 MB)
    char* ws = (char*)d_ws;
    size_t off = 0;
    auto alloc = [&](size_t bytes) { void* p = ws + off;
                                     off = (off + bytes + 255) & ~(size_t)255; return p; };
    int* rp      = (int*)alloc((size_t)N * 4);
    int* part    = (int*)alloc(256 * 4);
    int* csr_c   = (int*)alloc((size_t)E * 4);
    ushort* xb   = (ushort*)alloc((size_t)N * DN * 2);
    ushort* whi0 = (ushort*)alloc((size_t)DN * DN * 2);
    ushort* wlo0 = (ushort*)alloc((size_t)DN * DN * 2);
    ushort* whi1 = (ushort*)alloc((size_t)DN * DN * 2);
    ushort* wlo1 = (ushort*)alloc((size_t)DN * DN * 2);

    int eblocks = (E + 255) / 256;
    int nblocks = (N + 255) / 256;   // 196 <= 256
    int ablocks = (N + 3) / 4;
    int gblocks = (N + 63) / 64;

    // CSR build
    hipMemsetAsync(rp, 0, (size_t)N * 4, stream);
    deg_count<<<eblocks, 256, 0, stream>>>(ei, rp, E);
    scan_phase1<<<nblocks, 256, 0, stream>>>(rp, part, N);
    scan_phase2<<<1, 256, 0, stream>>>(part, nblocks);
    scan_phase3<<<nblocks, 256, 0, stream>>>(rp, part, N);
    csr_fill<<<eblocks, 256, 0, stream>>>(ei, rp, csr_c, E);

    // casts
    cast_f32_bf16<<<(N * DN / 8 + 255) / 256, 256, 0, stream>>>(x, xb, N * DN / 8);
    cast_split<<<(DN * DN / 4 + 255) / 256, 256, 0, stream>>>(W0, whi0, wlo0, DN * DN / 4);
    cast_split<<<(DN * DN / 4 + 255) / 256, 256, 0, stream>>>(W1, whi1, wlo1, DN * DN / 4);

    // layer 1: y1 packed into d_out; gemm in-place -> h1 fp32 (d_out) + h1 bf16 (xb)
    aggregate_packed<<<ablocks, 256, 0, stream>>>(x, xb, rp, csr_c, outp, N);
    gemm_ln_silu_mfma<<<gblocks, 256, 0, stream>>>(outp, whi0, wlo0,
                                                   b0, g0, be0, out, xb, N);
    // layer 2: self fp32 from d_out, neighbors bf16 from xb; gemm in-place -> final
    aggregate_packed<<<ablocks, 256, 0, stream>>>(out, xb, rp, csr_c, outp, N);
    gemm_ln_silu_mfma<<<gblocks, 256, 0, stream>>>(outp, whi1, wlo1,
                                                   b1, g1, be1, out, nullptr, N);
}

// Round 8
// 548.691 us; speedup vs baseline: 20.7538x; 1.2897x over previous
//
#include <hip/hip_runtime.h>
#include <math.h>

#define DN 256
#define LN_EPS 1e-5f

using f32x4  = __attribute__((ext_vector_type(4))) float;
using short8 = __attribute__((ext_vector_type(8))) short;

__device__ __forceinline__ ushort f2bf(float f) {
    uint u = __float_as_uint(f);
    u += 0x7fff + ((u >> 16) & 1);           // round-to-nearest-even
    return (ushort)(u >> 16);
}
__device__ __forceinline__ float bf2f(ushort h) { return __uint_as_float((uint)h << 16); }
__device__ __forceinline__ float bf_lo(uint u) { return __uint_as_float(u << 16); }
__device__ __forceinline__ float bf_hi(uint u) { return __uint_as_float(u & 0xffff0000u); }

// ---------------- x -> bf16 cast (neighbor-gather source) ----------------
__global__ __launch_bounds__(256) void cast_f32_bf16(const float* __restrict__ src,
                                                     ushort* __restrict__ dst, int n8) {
    int i = blockIdx.x * 256 + threadIdx.x;
    if (i >= n8) return;
    float4 a = reinterpret_cast<const float4*>(src)[2 * i];
    float4 b = reinterpret_cast<const float4*>(src)[2 * i + 1];
    uint4 o;
    o.x = (uint)f2bf(a.x) | ((uint)f2bf(a.y) << 16);
    o.y = (uint)f2bf(a.z) | ((uint)f2bf(a.w) << 16);
    o.z = (uint)f2bf(b.x) | ((uint)f2bf(b.y) << 16);
    o.w = (uint)f2bf(b.z) | ((uint)f2bf(b.w) << 16);
    reinterpret_cast<uint4*>(dst)[i] = o;
}

// ---------------- W split cast: f32 -> bf16 hi + bf16 lo ----------------
__global__ __launch_bounds__(256) void cast_split(const float* __restrict__ src,
                                                  ushort* __restrict__ hi,
                                                  ushort* __restrict__ lo, int n4) {
    int i = blockIdx.x * 256 + threadIdx.x;
    if (i >= n4) return;
    float4 a = reinterpret_cast<const float4*>(src)[i];
    ushort h0 = f2bf(a.x), h1 = f2bf(a.y), h2 = f2bf(a.z), h3 = f2bf(a.w);
    uint2 ho, lu;
    ho.x = (uint)h0 | ((uint)h1 << 16);
    ho.y = (uint)h2 | ((uint)h3 << 16);
    lu.x = (uint)f2bf(a.x - bf2f(h0)) | ((uint)f2bf(a.y - bf2f(h1)) << 16);
    lu.y = (uint)f2bf(a.z - bf2f(h2)) | ((uint)f2bf(a.w - bf2f(h3)) << 16);
    reinterpret_cast<uint2*>(hi)[i] = ho;
    reinterpret_cast<uint2*>(lo)[i] = lu;
}

// ---------------- CSR construction ----------------
__global__ __launch_bounds__(256) void deg_count(const int* __restrict__ ei,
                                                 int* __restrict__ rp, int E) {
    int e = blockIdx.x * 256 + threadIdx.x;
    if (e < E) atomicAdd(&rp[ei[e]], 1);
}

__global__ __launch_bounds__(256) void scan_phase1(int* __restrict__ rp,
                                                   int* __restrict__ part, int N) {
    __shared__ int wsum[4];
    int tid = threadIdx.x, lane = tid & 63, w = tid >> 6;
    int i = blockIdx.x * 256 + tid;
    int v = (i < N) ? rp[i] : 0;
    int s = v;
#pragma unroll
    for (int m = 1; m < 64; m <<= 1) {
        int t = __shfl_up(s, m);
        if (lane >= m) s += t;
    }
    if (lane == 63) wsum[w] = s;
    __syncthreads();
    int woff = 0;
    for (int k = 0; k < w; ++k) woff += wsum[k];
    if (i < N) rp[i] = woff + s - v;
    if (tid == 255) part[blockIdx.x] = woff + s;
}

__global__ __launch_bounds__(256) void scan_phase2(int* __restrict__ part, int nblk) {
    __shared__ int wsum[4];
    int tid = threadIdx.x, lane = tid & 63, w = tid >> 6;
    int v = (tid < nblk) ? part[tid] : 0;
    int s = v;
#pragma unroll
    for (int m = 1; m < 64; m <<= 1) {
        int t = __shfl_up(s, m);
        if (lane >= m) s += t;
    }
    if (lane == 63) wsum[w] = s;
    __syncthreads();
    int woff = 0;
    for (int k = 0; k < w; ++k) woff += wsum[k];
    if (tid < nblk) part[tid] = woff + s - v;
}

__global__ __launch_bounds__(256) void scan_phase3(int* __restrict__ rp,
                                                   const int* __restrict__ part, int N) {
    int i = blockIdx.x * 256 + threadIdx.x;
    if (i < N) rp[i] += part[blockIdx.x];
}

__global__ __launch_bounds__(256) void csr_fill(const int* __restrict__ ei,
                                                int* __restrict__ rp,
                                                int* __restrict__ csr_col, int E) {
    int e = blockIdx.x * 256 + threadIdx.x;
    if (e < E) {
        int pos = atomicAdd(&rp[ei[e]], 1);
        csr_col[pos] = ei[E + e];
    }
}

// ---------------- aggregation: y = self(fp32) + mean(neighbors bf16) ----------------
// writes y as split bf16 PACKED per row: [256 hi][256 lo] (1024B = fp32 row size).
// out_packed may alias xf_self (read-before-write within the owning wave only).
__global__ __launch_bounds__(256) void aggregate_packed(const float* xf_self,
                                                        const ushort* __restrict__ xb_neigh,
                                                        const int* __restrict__ rp_end,
                                                        const int* __restrict__ csr_col,
                                                        ushort* out_packed, int N) {
    int wid  = (blockIdx.x * 256 + threadIdx.x) >> 6;
    int lane = threadIdx.x & 63;
    if (wid >= N) return;
    int start = (wid == 0) ? 0 : rp_end[wid - 1];
    int end   = rp_end[wid];

    float4 xv = reinterpret_cast<const float4*>(xf_self + (size_t)wid * DN)[lane];

    float a0 = 0.f, a1 = 0.f, a2 = 0.f, a3 = 0.f;
    int j = start;
    for (; j + 8 <= end; j += 8) {
        uint2 v[8];
#pragma unroll
        for (int q = 0; q < 8; ++q) {
            int c = csr_col[j + q];
            v[q] = *reinterpret_cast<const uint2*>(xb_neigh + (size_t)c * DN + lane * 4);
        }
#pragma unroll
        for (int q = 0; q < 8; ++q) {
            a0 += bf_lo(v[q].x); a1 += bf_hi(v[q].x);
            a2 += bf_lo(v[q].y); a3 += bf_hi(v[q].y);
        }
    }
    for (; j < end; ++j) {
        int c = csr_col[j];
        uint2 v = *reinterpret_cast<const uint2*>(xb_neigh + (size_t)c * DN + lane * 4);
        a0 += bf_lo(v.x); a1 += bf_hi(v.x); a2 += bf_lo(v.y); a3 += bf_hi(v.y);
    }
    int deg = end - start;
    float inv = (deg > 0) ? 1.0f / (float)deg : 0.0f;
    float y0 = xv.x + a0 * inv, y1 = xv.y + a1 * inv;
    float y2 = xv.z + a2 * inv, y3 = xv.w + a3 * inv;
    ushort h0 = f2bf(y0), h1 = f2bf(y1), h2 = f2bf(y2), h3 = f2bf(y3);
    uint2 ho, lu;
    ho.x = (uint)h0 | ((uint)h1 << 16);
    ho.y = (uint)h2 | ((uint)h3 << 16);
    lu.x = (uint)f2bf(y0 - bf2f(h0)) | ((uint)f2bf(y1 - bf2f(h1)) << 16);
    lu.y = (uint)f2bf(y2 - bf2f(h2)) | ((uint)f2bf(y3 - bf2f(h3)) << 16);
    ushort* row = out_packed + (size_t)wid * 512;
    *reinterpret_cast<uint2*>(row + lane * 4) = ho;          // hi section [0,256)
    *reinterpret_cast<uint2*>(row + 256 + lane * 4) = lu;    // lo section [256,512)
}

// ---------------- split-precision MFMA GEMM + LayerNorm + SiLU ----------------
// h = (yhi+ylo) @ (Whi+Wlo)^T + b, dropping only the ylo*Wlo (eps^2) term.
// 512 threads = 8 waves, 128 rows/block. W in 8 x 32KB K-slices (4 hi + 4 lo),
// double-buffered ping-pong LDS, 1 barrier per slice, loads overlap MFMA.
// XOR swizzle applied identically on ds_write and ds_read (round-5-proven).
__global__ __launch_bounds__(512) void gemm_ln_silu_mfma(
        const ushort* yb, const ushort* __restrict__ whi, const ushort* __restrict__ wlo,
        const float* __restrict__ bias, const float* __restrict__ gam,
        const float* __restrict__ bet,
        float* outf, ushort* __restrict__ outb, int N) {
    __shared__ uint4 wl4[2][2048];              // 2 x 32 KB ping-pong

    int tid = threadIdx.x;
    int w = tid >> 6, lane = tid & 63;
    int g = lane >> 4, c0 = lane & 15;
    int n0 = blockIdx.x * 128;

    // prefetch all A-frags (K=256 -> 8 k-steps of 32), hi and lo, packed layout
    int arow = n0 + w * 16 + c0;
    bool av = arow < N;
    const ushort* ah = yb + (size_t)arow * 512 + g * 8;
    short8 zz = {0, 0, 0, 0, 0, 0, 0, 0};
    short8 ahi[8], alo[8];
#pragma unroll
    for (int kk = 0; kk < 8; ++kk) {
        ahi[kk] = av ? *reinterpret_cast<const short8*>(ah + kk * 32) : zz;
        alo[kk] = av ? *reinterpret_cast<const short8*>(ah + 256 + kk * 32) : zz;
    }

    f32x4 acc[16];
#pragma unroll
    for (int t = 0; t < 16; ++t) acc[t] = (f32x4){0.f, 0.f, 0.f, 0.f};

    uint4 streg[4];
    // prologue: stage slice 0 (whi, k 0..63) into buf 0
#pragma unroll
    for (int i = 0; i < 4; ++i) {
        int chunk = tid + 512 * i;              // 0..2047
        int j = chunk >> 3, kb = chunk & 7;
        streg[i] = *reinterpret_cast<const uint4*>(whi + (size_t)j * DN + kb * 8);
    }
#pragma unroll
    for (int i = 0; i < 4; ++i) {
        int chunk = tid + 512 * i;
        int j = chunk >> 3, kb = chunk & 7;
        int dst = ((j * 128 + kb * 16) ^ ((j & 7) << 4)) >> 4;
        wl4[0][dst] = streg[i];
    }
    __syncthreads();

#pragma unroll
    for (int st = 0; st < 8; ++st) {
        int cur = st & 1;
        // issue global loads for slice st+1 (hidden under the MFMAs below)
        if (st < 7) {
            const ushort* wsrc = (st + 1 < 4) ? whi : wlo;
            int k0 = ((st + 1) & 3) * 64;
#pragma unroll
            for (int i = 0; i < 4; ++i) {
                int chunk = tid + 512 * i;
                int j = chunk >> 3, kb = chunk & 7;
                streg[i] = *reinterpret_cast<const uint4*>(wsrc + (size_t)j * DN + k0 + kb * 8);
            }
        }
        // compute on buf cur: K-slice (st&3)*64 .. +63, hi slices get both A terms
        {
            char* wl = (char*)wl4[cur];
            int sl = st & 3;
#pragma unroll
            for (int kk = 0; kk < 2; ++kk) {
                int ks = sl * 2 + kk;
                int off = (kk * 4 + g) * 16;    // byte offset within 128B row
#pragma unroll
                for (int t = 0; t < 16; ++t) {
                    int j = t * 16 + c0;
                    int addr = (j * 128 + off) ^ ((j & 7) << 4);
                    short8 bfr = *reinterpret_cast<const short8*>(wl + addr);
                    acc[t] = __builtin_amdgcn_mfma_f32_16x16x32_bf16(ahi[ks], bfr, acc[t], 0, 0, 0);
                    if (st < 4)
                        acc[t] = __builtin_amdgcn_mfma_f32_16x16x32_bf16(alo[ks], bfr, acc[t], 0, 0, 0);
                }
            }
        }
        // write slice st+1 into the other buffer (nobody reads it this slice)
        if (st < 7) {
#pragma unroll
            for (int i = 0; i < 4; ++i) {
                int chunk = tid + 512 * i;
                int j = chunk >> 3, kb = chunk & 7;
                int dst = ((j * 128 + kb * 16) ^ ((j & 7) << 4)) >> 4;
                wl4[cur ^ 1][dst] = streg[i];
            }
        }
        __syncthreads();
    }

    // epilogue: bias + LayerNorm + SiLU (fp32)
#pragma unroll
    for (int t = 0; t < 16; ++t) {
        float bb = bias[t * 16 + c0];
#pragma unroll
        for (int r = 0; r < 4; ++r) acc[t][r] += bb;
    }

    float s[4] = {0.f, 0.f, 0.f, 0.f};
#pragma unroll
    for (int t = 0; t < 16; ++t)
#pragma unroll
        for (int r = 0; r < 4; ++r) s[r] += acc[t][r];
#pragma unroll
    for (int r = 0; r < 4; ++r) {
#pragma unroll
        for (int m = 1; m < 16; m <<= 1) s[r] += __shfl_xor(s[r], m);
        s[r] *= (1.f / DN);                     // mu
    }
    float vv[4] = {0.f, 0.f, 0.f, 0.f};
#pragma unroll
    for (int t = 0; t < 16; ++t)
#pragma unroll
        for (int r = 0; r < 4; ++r) { float d = acc[t][r] - s[r]; vv[r] += d * d; }
#pragma unroll
    for (int r = 0; r < 4; ++r) {
#pragma unroll
        for (int m = 1; m < 16; m <<= 1) vv[r] += __shfl_xor(vv[r], m);
        vv[r] = rsqrtf(vv[r] * (1.f / DN) + LN_EPS);
    }

    float gvv[16], btt[16];
#pragma unroll
    for (int t = 0; t < 16; ++t) {
        gvv[t] = gam[t * 16 + c0];
        btt[t] = bet[t * 16 + c0];
    }
#pragma unroll
    for (int r = 0; r < 4; ++r) {
        int row = n0 + w * 16 + g * 4 + r;
        if (row >= N) continue;
#pragma unroll
        for (int t = 0; t < 16; ++t) {
            float hn = (acc[t][r] - s[r]) * vv[r] * gvv[t] + btt[t];
            float sil = hn / (1.f + __expf(-hn));
            size_t o = (size_t)row * DN + t * 16 + c0;
            outf[o] = sil;
            if (outb) outb[o] = f2bf(sil);
        }
    }
}

extern "C" void kernel_launch(void* const* d_in, const int* in_sizes, int n_in,
                              void* d_out, int out_size, void* d_ws, size_t ws_size,
                              hipStream_t stream) {
    const float* x  = (const float*)d_in[0];
    const int*   ei = (const int*)d_in[1];
    const float* W0 = (const float*)d_in[2];
    const float* b0 = (const float*)d_in[3];
    const float* g0 = (const float*)d_in[4];
    const float* be0 = (const float*)d_in[5];
    const float* W1 = (const float*)d_in[6];
    const float* b1 = (const float*)d_in[7];
    const float* g1 = (const float*)d_in[8];
    const float* be1 = (const float*)d_in[9];
    float* out = (float*)d_out;
    ushort* outp = (ushort*)d_out;              // packed split-y view of d_out

    int N = in_sizes[0] / DN;
    int E = in_sizes[1] / 2;

    // workspace: rp | part | csr | xb (x bf16, later h1 bf16) | W splits (~33 MB)
    char* ws = (char*)d_ws;
    size_t off = 0;
    auto alloc = [&](size_t bytes) { void* p = ws + off;
                                     off = (off + bytes + 255) & ~(size_t)255; return p; };
    int* rp      = (int*)alloc((size_t)N * 4);
    int* part    = (int*)alloc(256 * 4);
    int* csr_c   = (int*)alloc((size_t)E * 4);
    ushort* xb   = (ushort*)alloc((size_t)N * DN * 2);
    ushort* whi0 = (ushort*)alloc((size_t)DN * DN * 2);
    ushort* wlo0 = (ushort*)alloc((size_t)DN * DN * 2);
    ushort* whi1 = (ushort*)alloc((size_t)DN * DN * 2);
    ushort* wlo1 = (ushort*)alloc((size_t)DN * DN * 2);

    int eblocks = (E + 255) / 256;
    int nblocks = (N + 255) / 256;   // 196 <= 256
    int ablocks = (N + 3) / 4;
    int gblocks = (N + 127) / 128;

    // CSR build
    hipMemsetAsync(rp, 0, (size_t)N * 4, stream);
    deg_count<<<eblocks, 256, 0, stream>>>(ei, rp, E);
    scan_phase1<<<nblocks, 256, 0, stream>>>(rp, part, N);
    scan_phase2<<<1, 256, 0, stream>>>(part, nblocks);
    scan_phase3<<<nblocks, 256, 0, stream>>>(rp, part, N);
    csr_fill<<<eblocks, 256, 0, stream>>>(ei, rp, csr_c, E);

    // casts
    cast_f32_bf16<<<(N * DN / 8 + 255) / 256, 256, 0, stream>>>(x, xb, N * DN / 8);
    cast_split<<<(DN * DN / 4 + 255) / 256, 256, 0, stream>>>(W0, whi0, wlo0, DN * DN / 4);
    cast_split<<<(DN * DN / 4 + 255) / 256, 256, 0, stream>>>(W1, wlo1 == nullptr ? nullptr : whi1, wlo1, DN * DN / 4);

    // layer 1: y1 packed into d_out; gemm in-place -> h1 fp32 (d_out) + h1 bf16 (xb)
    aggregate_packed<<<ablocks, 256, 0, stream>>>(x, xb, rp, csr_c, outp, N);
    gemm_ln_silu_mfma<<<gblocks, 512, 0, stream>>>(outp, whi0, wlo0,
                                                   b0, g0, be0, out, xb, N);
    // layer 2: self fp32 from d_out, neighbors bf16 from xb; gemm in-place -> final
    aggregate_packed<<<ablocks, 256, 0, stream>>>(out, xb, rp, csr_c, outp, N);
    gemm_ln_silu_mfma<<<gblocks, 512, 0, stream>>>(outp, whi1, wlo1,
                                                   b1, g1, be1, out, nullptr, N);
}